// Round 6
// baseline (3031.569 us; speedup 1.0000x reference)
//
#include <hip/hip_runtime.h>
#include <stdint.h>

typedef unsigned short ushort_t;
typedef __bf16 bf16x8 __attribute__((ext_vector_type(8)));
typedef float f32x4 __attribute__((ext_vector_type(4)));

#define TOTAL_HW 20267

// reg-head fused channel mapping (26 channels -> 6 tensors in d_out), element offsets
__constant__ int d_RB[26] = {3242720,3242720,3242720,3242720, 3404856, 3445390,3445390,3445390,
                             3566992, 3607526,3607526,3607526,3607526,3607526,3607526,3607526,3607526,
                             3607526,3607526,3607526,3607526,3607526,3607526,3607526,3607526, 4256070};
__constant__ int d_RM[26] = {4,4,4,4, 1, 3,3,3, 1, 16,16,16,16,16,16,16,16,16,16,16,16,16,16,16,16, 1};
__constant__ int d_RC[26] = {0,1,2,3, 0, 0,1,2, 0, 0,1,2,3,4,5,6,7,8,9,10,11,12,13,14,15, 0};

__device__ __forceinline__ ushort_t f2bf(float f) {
    union { float f; uint32_t i; } x; x.f = f;
    uint32_t r = x.i + 0x7fffu + ((x.i >> 16) & 1u);   // RNE
    return (ushort_t)(r >> 16);
}

// ---- tower weight transpose: f32 W[oc][ic][3][3] -> bf16 Wt[tap][oc][ic] ----
__global__ __launch_bounds__(256) void wtrans_tower_k(const float* __restrict__ src,
                                                      ushort_t* __restrict__ dst)
{
    int id = blockIdx.x * 256 + threadIdx.x;   // 65536
    int oc = id >> 8, ic = id & 255;
    const float* s = src + (size_t)(oc * 256 + ic) * 9;
    ushort_t* d = dst + oc * 256 + ic;
    #pragma unroll
    for (int t = 0; t < 9; t++) d[t * 65536] = f2bf(s[t]);
}

// ---- cls head weight transpose: f32, 80 valid rows, zero-pad to 128 ----
__global__ __launch_bounds__(256) void wtrans_cls_k(const float* __restrict__ src,
                                                    ushort_t* __restrict__ dst)
{
    int id = blockIdx.x * 256 + threadIdx.x;   // 32768
    int oc = id >> 8, ic = id & 255;
    ushort_t* d = dst + oc * 256 + ic;
    if (oc < 80) {
        const float* s = src + (size_t)(oc * 256 + ic) * 9;
        #pragma unroll
        for (int t = 0; t < 9; t++) d[t * 32768] = f2bf(s[t]);
    } else {
        #pragma unroll
        for (int t = 0; t < 9; t++) d[t * 32768] = 0;
    }
}

// ---- reg heads fused weight transpose (f32): 26 rows from 6 tensors + bias gather ----
__global__ __launch_bounds__(256) void wtrans_reg_k(
    const float* bbox_w, const float* ctr_w, const float* dim_w,
    const float* ori_w,  const float* kp_w,  const float* depth_w,
    const float* bbox_b, const float* ctr_b, const float* dim_b,
    const float* ori_b,  const float* kp_b,  const float* depth_b,
    ushort_t* __restrict__ dst, float* __restrict__ RegBias)
{
    int id = blockIdx.x * 256 + threadIdx.x;   // 32768
    int oc = id >> 8, ic = id & 255;
    ushort_t* d = dst + oc * 256 + ic;
    if (oc < 26) {
        const float* s; int c;
        if (oc < 4)       { s = bbox_w;  c = oc; }
        else if (oc < 5)  { s = ctr_w;   c = 0; }
        else if (oc < 8)  { s = dim_w;   c = oc - 5; }
        else if (oc < 9)  { s = ori_w;   c = 0; }
        else if (oc < 25) { s = kp_w;    c = oc - 9; }
        else              { s = depth_w; c = 0; }
        const float* sp = s + (size_t)(c * 256 + ic) * 9;
        #pragma unroll
        for (int t = 0; t < 9; t++) d[t * 32768] = f2bf(sp[t]);
    } else {
        #pragma unroll
        for (int t = 0; t < 9; t++) d[t * 32768] = 0;
    }
    if (id < 26) {
        const float* b; int c;
        if (id < 4)       { b = bbox_b;  c = id; }
        else if (id < 5)  { b = ctr_b;   c = 0; }
        else if (id < 8)  { b = dim_b;   c = id - 5; }
        else if (id < 9)  { b = ori_b;   c = 0; }
        else if (id < 25) { b = kp_b;    c = id - 9; }
        else              { b = depth_b; c = 0; }
        RegBias[id] = b[c];
    }
}

// ---- pack one level: f32 NCHW -> bf16 unpadded NHWC (LDS transpose) ----
__global__ __launch_bounds__(256) void pack_k(const float* __restrict__ f,
                                              ushort_t* __restrict__ S, int HW, int PT)
{
    __shared__ ushort_t tile[64][65];
    int r = blockIdx.x;
    int per_n = PT * 4;
    int n = (r >= per_n) ? 1 : 0; r -= n * per_n;
    int pb = r >> 2, cb = r & 3;
    int p0 = pb * 64, c0 = cb * 64;
    int t = threadIdx.x;
    #pragma unroll
    for (int i = 0; i < 16; i++) {
        int idx = i * 256 + t; int cl = idx >> 6, pl = idx & 63;
        int p = p0 + pl; ushort_t v = 0;
        if (p < HW) v = f2bf(f[(size_t)(n * 256 + c0 + cl) * HW + p]);
        tile[cl][pl] = v;
    }
    __syncthreads();
    #pragma unroll
    for (int i = 0; i < 16; i++) {
        int idx = i * 256 + t; int pl = idx >> 6, cl = idx & 63;
        int p = p0 + pl;
        if (p < HW) S[((size_t)n * HW + p) * 256 + c0 + cl] = tile[cl][pl];
    }
}

// ---- conv3x3 implicit GEMM, one level, unpadded bf16 src (borders zero-filled) ----
// MODE 0: tower conv -> bf16 NHWC dst + fused GN stat atomics
// MODE 1: cls head (80ch) -> f32 d_out ; MODE 2: reg heads fused (26ch) -> f32 d_out
template<int MODE>
__global__ __launch_bounds__(256) void conv3_k(
    const ushort_t* __restrict__ src, const ushort_t* __restrict__ wt,
    const float* __restrict__ bias,
    void* __restrict__ dstv, float* __restrict__ stats,
    int H, int W, int HW, int ntiles, int loff)
{
    constexpr int OCPAD = (MODE == 0) ? 256 : 128;
    __shared__ __align__(16) ushort_t As[128 * 64];
    __shared__ __align__(16) ushort_t Bs[128 * 64];

    int bid = blockIdx.x;
    int oc0 = (MODE == 0) ? blockIdx.y * 128 : 0;
    int n = (bid >= ntiles) ? 1 : 0;
    int tile = bid - n * ntiles;
    int px0 = tile * 128;
    const ushort_t* sbase = src + (size_t)n * HW * 256;

    int tid = threadIdx.x, wv = tid >> 6, ln = tid & 63;
    int wr = wv >> 1, wc = wv & 1;
    int srow = tid >> 3, scb = tid & 7;
    int ssc = (scb ^ (srow & 7)) * 8;

    int py[4], pxx[4], boff[4];
    #pragma unroll
    for (int j = 0; j < 4; j++) {
        int row = j * 32 + srow;
        int p = px0 + row; if (p > HW - 1) p = HW - 1;
        py[j] = p / W; pxx[j] = p - py[j] * W;
        boff[j] = (oc0 + row) * 256;
    }

    f32x4 acc[4][4];
    #pragma unroll
    for (int mi = 0; mi < 4; mi++)
        #pragma unroll
        for (int ni = 0; ni < 4; ni++) acc[mi][ni] = f32x4{0.f, 0.f, 0.f, 0.f};

    for (int tap = 0; tap < 9; ++tap) {
        int ky = tap / 3, kx = tap - ky * 3;
        int dy = ky - 1, dx = kx - 1;
        for (int kc = 0; kc < 4; ++kc) {
            int kco = kc * 64 + scb * 8;
            const ushort_t* wb = wt + tap * (OCPAD * 256) + kco;
            uint4 av[4], bv[4];
            #pragma unroll
            for (int j = 0; j < 4; j++) {
                int yy = py[j] + dy, xx = pxx[j] + dx;
                bool v = (yy >= 0) & (yy < H) & (xx >= 0) & (xx < W);
                av[j] = v ? *(const uint4*)(sbase + (yy * W + xx) * 256 + kco)
                          : uint4{0u, 0u, 0u, 0u};
                bv[j] = *(const uint4*)(wb + boff[j]);
            }
            #pragma unroll
            for (int j = 0; j < 4; j++) {
                int row = j * 32 + srow;
                *(uint4*)(As + row * 64 + ssc) = av[j];
                *(uint4*)(Bs + row * 64 + ssc) = bv[j];
            }
            __syncthreads();
            #pragma unroll
            for (int ks = 0; ks < 2; ks++) {
                bf16x8 af[4], bg[4];
                #pragma unroll
                for (int mi = 0; mi < 4; mi++) {
                    int rA = wr * 64 + mi * 16 + (ln & 15);
                    int blk = (ks * 4 + (ln >> 4)) ^ (ln & 7);
                    af[mi] = *(const bf16x8*)(As + rA * 64 + blk * 8);
                }
                #pragma unroll
                for (int ni = 0; ni < 4; ni++) {
                    int rB = wc * 64 + ni * 16 + (ln & 15);
                    int blk = (ks * 4 + (ln >> 4)) ^ (ln & 7);
                    bg[ni] = *(const bf16x8*)(Bs + rB * 64 + blk * 8);
                }
                #pragma unroll
                for (int mi = 0; mi < 4; mi++)
                    #pragma unroll
                    for (int ni = 0; ni < 4; ni++)
                        acc[mi][ni] = __builtin_amdgcn_mfma_f32_16x16x32_bf16(af[mi], bg[ni], acc[mi][ni], 0, 0, 0);
            }
            __syncthreads();
        }
    }

    if (MODE == 0) {
        ushort_t* obase = (ushort_t*)dstv + (size_t)n * HW * 256;
        #pragma unroll
        for (int ni = 0; ni < 4; ni++) {
            int oc = oc0 + wc * 64 + ni * 16 + (ln & 15);
            float bv = bias[oc];
            float s = 0.f, q = 0.f;
            #pragma unroll
            for (int mi = 0; mi < 4; mi++) {
                int pb = px0 + wr * 64 + mi * 16 + ((ln >> 4) << 2);
                #pragma unroll
                for (int rr2 = 0; rr2 < 4; rr2++) {
                    int p = pb + rr2;
                    if (p < HW) {
                        float v = acc[mi][ni][rr2] + bv;
                        obase[p * 256 + oc] = f2bf(v);
                        s += v; q += v * v;
                    }
                }
            }
            s += __shfl_xor(s, 16, 64); q += __shfl_xor(q, 16, 64);
            s += __shfl_xor(s, 32, 64); q += __shfl_xor(q, 32, 64);
            s += __shfl_xor(s, 1, 64);  q += __shfl_xor(q, 1, 64);
            s += __shfl_xor(s, 2, 64);  q += __shfl_xor(q, 2, 64);
            s += __shfl_xor(s, 4, 64);  q += __shfl_xor(q, 4, 64);
            if (ln == 0 || ln == 8) {
                int g = (oc0 + wc * 64 + ni * 16 + (ln & 8)) >> 3;
                float* st = stats + (n * 32 + g) * 2;
                atomicAdd(st, s); atomicAdd(st + 1, q);
            }
        }
    } else {
        float* dst = (float*)dstv;
        #pragma unroll
        for (int ni = 0; ni < 4; ni++) {
            int oc = wc * 64 + ni * 16 + (ln & 15);
            if (MODE == 1 ? (oc < 80) : (oc < 26)) {
                float bv = bias[oc];
                int rb = 0, rm = 80, rc = 0; bool rl = false;
                if (MODE == 2) { rb = d_RB[oc]; rm = d_RM[oc]; rc = d_RC[oc]; rl = (oc < 4); }
                #pragma unroll
                for (int mi = 0; mi < 4; mi++) {
                    int pb = px0 + wr * 64 + mi * 16 + ((ln >> 4) << 2);
                    #pragma unroll
                    for (int rr2 = 0; rr2 < 4; rr2++) {
                        int p = pb + rr2;
                        if (p < HW) {
                            float v = acc[mi][ni][rr2] + bv;
                            if (rl) v = fmaxf(v, 0.f);
                            int pg = n * TOTAL_HW + loff + p;
                            if (MODE == 1) dst[(size_t)pg * 80 + oc] = v;
                            else           dst[rb + (size_t)pg * rm + rc] = v;
                        }
                    }
                }
            }
        }
    }
}

// ---- GroupNorm finalize + affine (f32 params) + relu, in place, one level ----
__global__ __launch_bounds__(256) void norm_k(
    ushort_t* __restrict__ buf, const float* __restrict__ stats,
    const float* __restrict__ gw, const float* __restrict__ gb, int HW)
{
    int u = blockIdx.x * 256 + threadIdx.x;
    if (u >= HW * 64) return;
    int per_n = HW * 32;
    int n = (u >= per_n) ? 1 : 0; int r = u - n * per_n;
    int p = r >> 5, g = r & 31;
    const float* st = stats + (n * 32 + g) * 2;
    float cnt = 8.0f * (float)HW;
    float mean = st[0] / cnt;
    float var = st[1] / cnt - mean * mean;
    float inv = rsqrtf(fmaxf(var, 0.f) + 1e-5f);
    ushort_t* ptr = buf + ((size_t)n * HW + p) * 256 + g * 8;
    uint4 din = *(const uint4*)ptr;
    uint4 dout;
    const ushort_t* xi = (const ushort_t*)&din;
    ushort_t* oi = (ushort_t*)&dout;
    #pragma unroll
    for (int i = 0; i < 8; i++) {
        union { uint32_t ii; float ff; } cv; cv.ii = ((uint32_t)xi[i]) << 16;
        float v = (cv.ff - mean) * inv * gw[g * 8 + i] + gb[g * 8 + i];
        oi[i] = f2bf(fmaxf(v, 0.f));
    }
    *(uint4*)ptr = dout;
}

// ---------------- ws layout (bytes), total ~39.8 MB ----------------
// Stats (f32)   : 0 .. 20,480            (40 slots x 128 f32)
// RegBias (f32) : 20,480 .. 20,608
// TowerWtAll    : 20,608 .. 9,457,792    (8 layers x 589,824 bf16)
// WtCls         : 9,457,792 .. 10,047,616
// WtReg         : 10,047,616 .. 10,637,440
// S             : 10,637,440 .. 26,202,240  (2 x 15200 x 256 bf16)
// D             : 26,202,240 .. 41,767,040

extern "C" void kernel_launch(void* const* d_in, const int* in_sizes, int n_in,
                              void* d_out, int out_size, void* d_ws, size_t ws_size,
                              hipStream_t stream) {
    const float* feats[5] = {(const float*)d_in[0], (const float*)d_in[1],
                             (const float*)d_in[2], (const float*)d_in[3],
                             (const float*)d_in[4]};
    const float* cls_conv_w = (const float*)d_in[5];
    const float* cls_conv_b = (const float*)d_in[6];
    const float* cls_gn_w   = (const float*)d_in[7];
    const float* cls_gn_b   = (const float*)d_in[8];
    const float* cls_out_w  = (const float*)d_in[9];
    const float* cls_out_b  = (const float*)d_in[10];
    const float* reg_conv_w = (const float*)d_in[11];
    const float* reg_conv_b = (const float*)d_in[12];
    const float* reg_gn_w   = (const float*)d_in[13];
    const float* reg_gn_b   = (const float*)d_in[14];

    char* wsb = (char*)d_ws;
    float* Stats     = (float*)wsb;
    float* RegBias   = (float*)(wsb + 20480);
    ushort_t* TowerWtAll = (ushort_t*)(wsb + 20608);
    ushort_t* WtCls  = (ushort_t*)(wsb + 9457792);
    ushort_t* WtReg  = (ushort_t*)(wsb + 10047616);
    ushort_t* S      = (ushort_t*)(wsb + 10637440);
    ushort_t* D      = (ushort_t*)(wsb + 26202240);
    float* outf      = (float*)d_out;

    const int Hs[5]  = {100, 50, 25, 13, 7};
    const int Ws_[5] = {152, 76, 38, 19, 10};
    const int HWs[5] = {15200, 3800, 950, 247, 70};
    const int TLs[5] = {119, 30, 8, 2, 1};       // ceil(HW/128)
    const int PTs[5] = {238, 60, 15, 4, 2};      // ceil(HW/64)
    const int LOFFs[5] = {0, 15200, 19000, 19950, 20197};

    hipMemsetAsync(d_ws, 0, 20608, stream);      // Stats + RegBias

    // weight prep (once)
    for (int tw = 0; tw < 2; tw++) {
        const float* conv_w = tw ? reg_conv_w : cls_conv_w;
        for (int L = 0; L < 4; L++)
            wtrans_tower_k<<<256, 256, 0, stream>>>(conv_w + (size_t)L * 589824,
                                                    TowerWtAll + (size_t)(tw * 4 + L) * 589824);
    }
    wtrans_cls_k<<<128, 256, 0, stream>>>(cls_out_w, WtCls);
    wtrans_reg_k<<<128, 256, 0, stream>>>(
        (const float*)d_in[15], (const float*)d_in[17], (const float*)d_in[19],
        (const float*)d_in[21], (const float*)d_in[23], (const float*)d_in[25],
        (const float*)d_in[16], (const float*)d_in[18], (const float*)d_in[20],
        (const float*)d_in[22], (const float*)d_in[24], (const float*)d_in[26],
        WtReg, RegBias);

    for (int tw = 0; tw < 2; tw++) {
        const float* conv_b = tw ? reg_conv_b : cls_conv_b;
        const float* gn_w   = tw ? reg_gn_w   : cls_gn_w;
        const float* gn_b   = tw ? reg_gn_b   : cls_gn_b;

        for (int l = 0; l < 5; l++) {
            int H = Hs[l], W = Ws_[l], HW = HWs[l], TL = TLs[l];
            pack_k<<<PTs[l] * 8, 256, 0, stream>>>(feats[l], S, HW, PTs[l]);
            ushort_t* cur = S;
            ushort_t* oth = D;
            for (int L = 0; L < 4; L++) {
                float* st = Stats + (size_t)((tw * 4 + L) * 5 + l) * 128;
                conv3_k<0><<<dim3(2 * TL, 2), 256, 0, stream>>>(
                    cur, TowerWtAll + (size_t)(tw * 4 + L) * 589824,
                    conv_b + L * 256, oth, st, H, W, HW, TL, 0);
                norm_k<<<(HW * 64 + 255) / 256, 256, 0, stream>>>(
                    oth, st, gn_w + L * 256, gn_b + L * 256, HW);
                ushort_t* t = cur; cur = oth; oth = t;
            }
            if (tw == 0)
                conv3_k<1><<<dim3(2 * TL, 1), 256, 0, stream>>>(
                    cur, WtCls, cls_out_b, outf, nullptr, H, W, HW, TL, LOFFs[l]);
            else
                conv3_k<2><<<dim3(2 * TL, 1), 256, 0, stream>>>(
                    cur, WtReg, RegBias, outf, nullptr, H, W, HW, TL, LOFFs[l]);
        }
    }
}

// Round 7
// 1084.846 us; speedup vs baseline: 2.7945x; 2.7945x over previous
//
#include <hip/hip_runtime.h>
#include <stdint.h>

typedef unsigned short ushort_t;
typedef __bf16 bf16x8 __attribute__((ext_vector_type(8)));
typedef float f32x4 __attribute__((ext_vector_type(4)));

#define TOTAL_HW 20267
#define PTOT 21267          // padded pyramid pixels per batch

// reg-head fused channel mapping (26 channels -> 6 tensors in d_out), f32 element offsets
__constant__ int d_RB[26] = {3242720,3242720,3242720,3242720, 3404856, 3445390,3445390,3445390,
                             3566992, 3607526,3607526,3607526,3607526,3607526,3607526,3607526,3607526,
                             3607526,3607526,3607526,3607526,3607526,3607526,3607526,3607526, 4256070};
__constant__ int d_RM[26] = {4,4,4,4, 1, 3,3,3, 1, 16,16,16,16,16,16,16,16,16,16,16,16,16,16,16,16, 1};
__constant__ int d_RC[26] = {0,1,2,3, 0, 0,1,2, 0, 0,1,2,3,4,5,6,7,8,9,10,11,12,13,14,15, 0};

// level geometry
__constant__ int F_TC[6]   = {0,238,298,314,318,320};
__constant__ int F_TL[5]   = {119,30,8,2,1};
__constant__ int F_H[5]    = {100,50,25,13,7};
__constant__ int F_W[5]    = {152,76,38,19,10};
__constant__ int F_HW[5]   = {15200,3800,950,247,70};
__constant__ int F_PB[5]   = {0,15708,19764,20844,21159};   // padded pixel base within batch
__constant__ int F_LOFF[5] = {0,15200,19000,19950,20197};

__device__ __forceinline__ ushort_t f2bf(float f) {
    union { float f; uint32_t i; } x; x.f = f;
    uint32_t r = x.i + 0x7fffu + ((x.i >> 16) & 1u);   // RNE
    return (ushort_t)(r >> 16);
}
__device__ __forceinline__ float bf2f(ushort_t u) {
    union { uint32_t i; float f; } x; x.i = ((uint32_t)u) << 16; return x.f;
}
__device__ __forceinline__ void gld16(const ushort_t* g, ushort_t* lds) {
    __builtin_amdgcn_global_load_lds((const __attribute__((address_space(1))) void*)g,
                                     (__attribute__((address_space(3))) void*)lds, 16, 0, 0);
}

// ================= weight prep (shared by both paths) =================
__global__ __launch_bounds__(256) void wtrans_tower_k(const float* __restrict__ src,
                                                      ushort_t* __restrict__ dst)
{
    int id = blockIdx.x * 256 + threadIdx.x;   // 65536
    int oc = id >> 8, ic = id & 255;
    const float* s = src + (size_t)(oc * 256 + ic) * 9;
    ushort_t* d = dst + oc * 256 + ic;
    #pragma unroll
    for (int t = 0; t < 9; t++) d[t * 65536] = f2bf(s[t]);
}
__global__ __launch_bounds__(256) void wtrans_cls_k(const float* __restrict__ src,
                                                    ushort_t* __restrict__ dst)
{
    int id = blockIdx.x * 256 + threadIdx.x;   // 32768
    int oc = id >> 8, ic = id & 255;
    ushort_t* d = dst + oc * 256 + ic;
    if (oc < 80) {
        const float* s = src + (size_t)(oc * 256 + ic) * 9;
        #pragma unroll
        for (int t = 0; t < 9; t++) d[t * 32768] = f2bf(s[t]);
    } else {
        #pragma unroll
        for (int t = 0; t < 9; t++) d[t * 32768] = 0;
    }
}
__global__ __launch_bounds__(256) void wtrans_reg_k(
    const float* bbox_w, const float* ctr_w, const float* dim_w,
    const float* ori_w,  const float* kp_w,  const float* depth_w,
    const float* bbox_b, const float* ctr_b, const float* dim_b,
    const float* ori_b,  const float* kp_b,  const float* depth_b,
    ushort_t* __restrict__ dst, float* __restrict__ RegBias)
{
    int id = blockIdx.x * 256 + threadIdx.x;   // 32768
    int oc = id >> 8, ic = id & 255;
    ushort_t* d = dst + oc * 256 + ic;
    if (oc < 26) {
        const float* s; int c;
        if (oc < 4)       { s = bbox_w;  c = oc; }
        else if (oc < 5)  { s = ctr_w;   c = 0; }
        else if (oc < 8)  { s = dim_w;   c = oc - 5; }
        else if (oc < 9)  { s = ori_w;   c = 0; }
        else if (oc < 25) { s = kp_w;    c = oc - 9; }
        else              { s = depth_w; c = 0; }
        const float* sp = s + (size_t)(c * 256 + ic) * 9;
        #pragma unroll
        for (int t = 0; t < 9; t++) d[t * 32768] = f2bf(sp[t]);
    } else {
        #pragma unroll
        for (int t = 0; t < 9; t++) d[t * 32768] = 0;
    }
    if (id < 26) {
        const float* b; int c;
        if (id < 4)       { b = bbox_b;  c = id; }
        else if (id < 5)  { b = ctr_b;   c = 0; }
        else if (id < 8)  { b = dim_b;   c = id - 5; }
        else if (id < 9)  { b = ori_b;   c = 0; }
        else if (id < 25) { b = kp_b;    c = id - 9; }
        else              { b = depth_b; c = 0; }
        RegBias[id] = b[c];
    }
}

// ================= FAST PATH =================
// pack all levels: f32 NCHW -> padded bf16 NHWC pyramid (pads pre-zeroed by memset)
__global__ __launch_bounds__(256) void packF_k(
    const float* f0, const float* f1, const float* f2,
    const float* f3, const float* f4, ushort_t* __restrict__ S)
{
    __shared__ ushort_t tile[64][65];
    const int PCUM[6] = {0, 1904, 2384, 2504, 2536, 2552};
    const int PT[5]   = {238, 60, 15, 4, 2};
    int bid = blockIdx.x;
    int l = 0;
    #pragma unroll
    for (int i = 1; i < 5; i++) if (bid >= PCUM[i]) l = i;
    int r = bid - PCUM[l];
    int per_n = PT[l] * 4;
    int n = (r >= per_n) ? 1 : 0; r -= n * per_n;
    int pb = r >> 2, cb = r & 3;
    const float* fs = f0;
    if (l == 1) fs = f1; else if (l == 2) fs = f2; else if (l == 3) fs = f3; else if (l == 4) fs = f4;
    int HW = F_HW[l], W = F_W[l], Wp = W + 2;
    int p0 = pb * 64, c0 = cb * 64;
    int t = threadIdx.x;
    #pragma unroll
    for (int i = 0; i < 16; i++) {
        int idx = i * 256 + t; int cl = idx >> 6, pl = idx & 63;
        int p = p0 + pl; ushort_t v = 0;
        if (p < HW) v = f2bf(fs[(size_t)(n * 256 + c0 + cl) * HW + p]);
        tile[cl][pl] = v;
    }
    __syncthreads();
    ushort_t* ob = S + ((size_t)n * PTOT + F_PB[l]) * 256;
    #pragma unroll
    for (int i = 0; i < 16; i++) {
        int idx = i * 256 + t; int pl = idx >> 6, cl = idx & 63;
        int p = p0 + pl;
        if (p < HW) {
            int y = p / W, x = p - y * W;
            ob[((y + 1) * Wp + (x + 1)) * 256 + c0 + cl] = tile[cl][pl];
        }
    }
}

// tower conv: all levels + both towers in one grid. 128px x 128oc tile, global_load_lds staging.
__global__ __launch_bounds__(256) void convT_k(
    const ushort_t* __restrict__ srcC, const ushort_t* __restrict__ srcR,
    ushort_t* __restrict__ dstC, ushort_t* __restrict__ dstR,
    const ushort_t* __restrict__ wtAll,
    const float* __restrict__ biasC, const float* __restrict__ biasR,
    float* __restrict__ stats, int L)
{
    __shared__ __align__(16) ushort_t As[128 * 64];
    __shared__ __align__(16) ushort_t Bs[128 * 64];

    int tw = blockIdx.z;
    const ushort_t* src = tw ? srcR : srcC;
    ushort_t* dst = tw ? dstR : dstC;
    const ushort_t* wt = wtAll + (size_t)(tw * 4 + L) * 589824;
    const float* bias = (tw ? biasR : biasC) + L * 256;

    int bid = blockIdx.x, oc0 = blockIdx.y * 128;
    int l = 0;
    #pragma unroll
    for (int i = 1; i < 5; i++) if (bid >= F_TC[i]) l = i;
    int r = bid - F_TC[l];
    int tl = F_TL[l];
    int n = (r >= tl) ? 1 : 0; int tile = r - n * tl;
    int W = F_W[l], HW = F_HW[l], Wp = W + 2;
    int px0 = tile * 128;
    const ushort_t* sbase = src + ((size_t)n * PTOT + F_PB[l]) * 256;
    ushort_t* obase = dst + ((size_t)n * PTOT + F_PB[l]) * 256;

    int tid = threadIdx.x, wv = tid >> 6, ln = tid & 63;
    int wr = wv >> 1, wc = wv & 1;
    int rr = ln >> 3;                       // within-wave row 0..7
    int swz = ((ln & 7) ^ rr) * 8;          // source-chunk swizzle (elements)

    int apix[4], boff[4];
    #pragma unroll
    for (int j = 0; j < 4; j++) {
        int row = j * 32 + wv * 8 + rr;
        int p = px0 + row; if (p > HW - 1) p = HW - 1;
        int y = p / W, x = p - y * W;
        apix[j] = ((y + 1) * Wp + (x + 1)) * 256;
        boff[j] = (oc0 + row) * 256;
    }

    f32x4 acc[4][4];
    #pragma unroll
    for (int mi = 0; mi < 4; mi++)
        #pragma unroll
        for (int ni = 0; ni < 4; ni++) acc[mi][ni] = f32x4{0.f, 0.f, 0.f, 0.f};

    for (int tap = 0; tap < 9; ++tap) {
        int ky = tap / 3, kx = tap - ky * 3;
        int tapo = ((ky - 1) * Wp + (kx - 1)) * 256;
        const ushort_t* wtap = wt + tap * 65536;
        for (int kc = 0; kc < 4; ++kc) {
            int kco = kc * 64 + swz;
            #pragma unroll
            for (int j = 0; j < 4; j++)
                gld16(sbase + apix[j] + tapo + kco, As + (j * 32 + wv * 8) * 64);
            #pragma unroll
            for (int j = 0; j < 4; j++)
                gld16(wtap + boff[j] + kco, Bs + (j * 32 + wv * 8) * 64);
            __syncthreads();
            #pragma unroll
            for (int ks = 0; ks < 2; ks++) {
                bf16x8 af[4], bg[4];
                #pragma unroll
                for (int mi = 0; mi < 4; mi++) {
                    int rA = wr * 64 + mi * 16 + (ln & 15);
                    int blk = (ks * 4 + (ln >> 4)) ^ (ln & 7);
                    af[mi] = *(const bf16x8*)(As + rA * 64 + blk * 8);
                }
                #pragma unroll
                for (int ni = 0; ni < 4; ni++) {
                    int rB = wc * 64 + ni * 16 + (ln & 15);
                    int blk = (ks * 4 + (ln >> 4)) ^ (ln & 7);
                    bg[ni] = *(const bf16x8*)(Bs + rB * 64 + blk * 8);
                }
                #pragma unroll
                for (int mi = 0; mi < 4; mi++)
                    #pragma unroll
                    for (int ni = 0; ni < 4; ni++)
                        acc[mi][ni] = __builtin_amdgcn_mfma_f32_16x16x32_bf16(af[mi], bg[ni], acc[mi][ni], 0, 0, 0);
            }
            __syncthreads();
        }
    }

    // epilogue: bias + padded store + GN stats
    #pragma unroll
    for (int ni = 0; ni < 4; ni++) {
        int oc = oc0 + wc * 64 + ni * 16 + (ln & 15);
        float bv = bias[oc];
        float s = 0.f, q = 0.f;
        #pragma unroll
        for (int mi = 0; mi < 4; mi++) {
            int pb = px0 + wr * 64 + mi * 16 + ((ln >> 4) << 2);
            if (pb < HW) {
                int y = pb / W, x = pb - y * W;
                #pragma unroll
                for (int rr2 = 0; rr2 < 4; rr2++) {
                    int p = pb + rr2;
                    if (p < HW) {
                        float v = acc[mi][ni][rr2] + bv;
                        obase[((y + 1) * Wp + (x + 1)) * 256 + oc] = f2bf(v);
                        s += v; q += v * v;
                    }
                    x++; if (x == W) { x = 0; y++; }
                }
            }
        }
        s += __shfl_xor(s, 16, 64); q += __shfl_xor(q, 16, 64);
        s += __shfl_xor(s, 32, 64); q += __shfl_xor(q, 32, 64);
        s += __shfl_xor(s, 1, 64);  q += __shfl_xor(q, 1, 64);
        s += __shfl_xor(s, 2, 64);  q += __shfl_xor(q, 2, 64);
        s += __shfl_xor(s, 4, 64);  q += __shfl_xor(q, 4, 64);
        if (ln == 0 || ln == 8) {
            int g = (oc0 + wc * 64 + ni * 16 + (ln & 8)) >> 3;
            float* st = stats + (size_t)((tw * 4 + L) * 5 + l) * 128 + (n * 32 + g) * 2;
            atomicAdd(st, s); atomicAdd(st + 1, q);
        }
    }
}

// head conv: z=0 cls (80ch), z=1 reg fused (26ch); OCPAD=128; f32 out
__global__ __launch_bounds__(256) void convH_k(
    const ushort_t* __restrict__ srcC, const ushort_t* __restrict__ srcR,
    const ushort_t* __restrict__ wtC, const ushort_t* __restrict__ wtR,
    const float* __restrict__ biasC, const float* __restrict__ biasR,
    float* __restrict__ outF)
{
    __shared__ __align__(16) ushort_t As[128 * 64];
    __shared__ __align__(16) ushort_t Bs[128 * 64];

    int mode = blockIdx.z;
    const ushort_t* src = mode ? srcR : srcC;
    const ushort_t* wt  = mode ? wtR  : wtC;
    const float* bias   = mode ? biasR : biasC;

    int bid = blockIdx.x;
    int l = 0;
    #pragma unroll
    for (int i = 1; i < 5; i++) if (bid >= F_TC[i]) l = i;
    int r = bid - F_TC[l];
    int tl = F_TL[l];
    int n = (r >= tl) ? 1 : 0; int tile = r - n * tl;
    int W = F_W[l], HW = F_HW[l], Wp = W + 2;
    int px0 = tile * 128;
    const ushort_t* sbase = src + ((size_t)n * PTOT + F_PB[l]) * 256;

    int tid = threadIdx.x, wv = tid >> 6, ln = tid & 63;
    int wr = wv >> 1, wc = wv & 1;
    int rr = ln >> 3;
    int swz = ((ln & 7) ^ rr) * 8;

    int apix[4], boff[4];
    #pragma unroll
    for (int j = 0; j < 4; j++) {
        int row = j * 32 + wv * 8 + rr;
        int p = px0 + row; if (p > HW - 1) p = HW - 1;
        int y = p / W, x = p - y * W;
        apix[j] = ((y + 1) * Wp + (x + 1)) * 256;
        boff[j] = row * 256;
    }

    f32x4 acc[4][4];
    #pragma unroll
    for (int mi = 0; mi < 4; mi++)
        #pragma unroll
        for (int ni = 0; ni < 4; ni++) acc[mi][ni] = f32x4{0.f, 0.f, 0.f, 0.f};

    for (int tap = 0; tap < 9; ++tap) {
        int ky = tap / 3, kx = tap - ky * 3;
        int tapo = ((ky - 1) * Wp + (kx - 1)) * 256;
        const ushort_t* wtap = wt + tap * 32768;
        for (int kc = 0; kc < 4; ++kc) {
            int kco = kc * 64 + swz;
            #pragma unroll
            for (int j = 0; j < 4; j++)
                gld16(sbase + apix[j] + tapo + kco, As + (j * 32 + wv * 8) * 64);
            #pragma unroll
            for (int j = 0; j < 4; j++)
                gld16(wtap + boff[j] + kco, Bs + (j * 32 + wv * 8) * 64);
            __syncthreads();
            #pragma unroll
            for (int ks = 0; ks < 2; ks++) {
                bf16x8 af[4], bg[4];
                #pragma unroll
                for (int mi = 0; mi < 4; mi++) {
                    int rA = wr * 64 + mi * 16 + (ln & 15);
                    int blk = (ks * 4 + (ln >> 4)) ^ (ln & 7);
                    af[mi] = *(const bf16x8*)(As + rA * 64 + blk * 8);
                }
                #pragma unroll
                for (int ni = 0; ni < 4; ni++) {
                    int rB = wc * 64 + ni * 16 + (ln & 15);
                    int blk = (ks * 4 + (ln >> 4)) ^ (ln & 7);
                    bg[ni] = *(const bf16x8*)(Bs + rB * 64 + blk * 8);
                }
                #pragma unroll
                for (int mi = 0; mi < 4; mi++)
                    #pragma unroll
                    for (int ni = 0; ni < 4; ni++)
                        acc[mi][ni] = __builtin_amdgcn_mfma_f32_16x16x32_bf16(af[mi], bg[ni], acc[mi][ni], 0, 0, 0);
            }
            __syncthreads();
        }
    }

    #pragma unroll
    for (int ni = 0; ni < 4; ni++) {
        int oc = wc * 64 + ni * 16 + (ln & 15);
        bool valid = mode ? (oc < 26) : (oc < 80);
        if (valid) {
            float bv = bias[oc];
            int rb = 0, rm = 80, rc = oc; bool rl = false;
            if (mode) { rb = d_RB[oc]; rm = d_RM[oc]; rc = d_RC[oc]; rl = (oc < 4); }
            #pragma unroll
            for (int mi = 0; mi < 4; mi++) {
                int pb = px0 + wr * 64 + mi * 16 + ((ln >> 4) << 2);
                #pragma unroll
                for (int rr2 = 0; rr2 < 4; rr2++) {
                    int p = pb + rr2;
                    if (p < HW) {
                        float v = acc[mi][ni][rr2] + bv;
                        if (rl) v = fmaxf(v, 0.f);
                        int pg = n * TOTAL_HW + F_LOFF[l] + p;
                        outF[rb + (size_t)pg * rm + rc] = v;
                    }
                }
            }
        }
    }
}

// merged GN finalize+affine+relu over both towers, all levels (in place, padded interior)
__global__ __launch_bounds__(256) void normF_k(
    ushort_t* __restrict__ bufC, ushort_t* __restrict__ bufR,
    const float* __restrict__ stats,
    const float* __restrict__ gwC, const float* __restrict__ gwR,
    const float* __restrict__ gbC, const float* __restrict__ gbR, int L)
{
    int u = blockIdx.x * 256 + threadIdx.x;
    if (u >= 2594176) return;                 // 2tw * 2n * 20267 * 32
    int tw = (u >= 1297088) ? 1 : 0; u -= tw * 1297088;
    int n = (u >= 648544) ? 1 : 0; u -= n * 648544;
    int cp = u >> 5, g = u & 31;
    int l = 0;
    #pragma unroll
    for (int i = 1; i < 5; i++) if (cp >= F_LOFF[i]) l = i;
    int p = cp - F_LOFF[l];
    int W = F_W[l], HW = F_HW[l];
    int y = p / W, x = p - y * W;
    const float* st = stats + (size_t)((tw * 4 + L) * 5 + l) * 128 + (n * 32 + g) * 2;
    float cnt = 8.0f * (float)HW;
    float mean = st[0] / cnt;
    float var = st[1] / cnt - mean * mean;
    float inv = rsqrtf(fmaxf(var, 0.f) + 1e-5f);
    const float* gw = (tw ? gwR : gwC) + L * 256 + g * 8;
    const float* gb = (tw ? gbR : gbC) + L * 256 + g * 8;
    ushort_t* buf = tw ? bufR : bufC;
    ushort_t* ptr = buf + (((size_t)n * PTOT + F_PB[l]) + (y + 1) * (W + 2) + (x + 1)) * 256 + g * 8;
    uint4 din = *(const uint4*)ptr;
    uint4 dout;
    const ushort_t* xi = (const ushort_t*)&din;
    ushort_t* oi = (ushort_t*)&dout;
    #pragma unroll
    for (int i = 0; i < 8; i++) {
        float v = (bf2f(xi[i]) - mean) * inv * gw[i] + gb[i];
        oi[i] = f2bf(fmaxf(v, 0.f));
    }
    *(uint4*)ptr = dout;
}

// ================= FALLBACK PATH (R6, proven) =================
__global__ __launch_bounds__(256) void packL_k(const float* __restrict__ f,
                                               ushort_t* __restrict__ S, int HW, int PT)
{
    __shared__ ushort_t tile[64][65];
    int r = blockIdx.x;
    int per_n = PT * 4;
    int n = (r >= per_n) ? 1 : 0; r -= n * per_n;
    int pb = r >> 2, cb = r & 3;
    int p0 = pb * 64, c0 = cb * 64;
    int t = threadIdx.x;
    #pragma unroll
    for (int i = 0; i < 16; i++) {
        int idx = i * 256 + t; int cl = idx >> 6, pl = idx & 63;
        int p = p0 + pl; ushort_t v = 0;
        if (p < HW) v = f2bf(f[(size_t)(n * 256 + c0 + cl) * HW + p]);
        tile[cl][pl] = v;
    }
    __syncthreads();
    #pragma unroll
    for (int i = 0; i < 16; i++) {
        int idx = i * 256 + t; int pl = idx >> 6, cl = idx & 63;
        int p = p0 + pl;
        if (p < HW) S[((size_t)n * HW + p) * 256 + c0 + cl] = tile[cl][pl];
    }
}

template<int MODE>
__global__ __launch_bounds__(256) void conv3L_k(
    const ushort_t* __restrict__ src, const ushort_t* __restrict__ wt,
    const float* __restrict__ bias,
    void* __restrict__ dstv, float* __restrict__ stats,
    int H, int W, int HW, int ntiles, int loff)
{
    constexpr int OCPAD = (MODE == 0) ? 256 : 128;
    __shared__ __align__(16) ushort_t As[128 * 64];
    __shared__ __align__(16) ushort_t Bs[128 * 64];
    int bid = blockIdx.x;
    int oc0 = (MODE == 0) ? blockIdx.y * 128 : 0;
    int n = (bid >= ntiles) ? 1 : 0;
    int tile = bid - n * ntiles;
    int px0 = tile * 128;
    const ushort_t* sbase = src + (size_t)n * HW * 256;
    int tid = threadIdx.x, wv = tid >> 6, ln = tid & 63;
    int wr = wv >> 1, wc = wv & 1;
    int srow = tid >> 3, scb = tid & 7;
    int ssc = (scb ^ (srow & 7)) * 8;
    int py[4], pxx[4], boff[4];
    #pragma unroll
    for (int j = 0; j < 4; j++) {
        int row = j * 32 + srow;
        int p = px0 + row; if (p > HW - 1) p = HW - 1;
        py[j] = p / W; pxx[j] = p - py[j] * W;
        boff[j] = (oc0 + row) * 256;
    }
    f32x4 acc[4][4];
    #pragma unroll
    for (int mi = 0; mi < 4; mi++)
        #pragma unroll
        for (int ni = 0; ni < 4; ni++) acc[mi][ni] = f32x4{0.f, 0.f, 0.f, 0.f};
    for (int tap = 0; tap < 9; ++tap) {
        int ky = tap / 3, kx = tap - ky * 3;
        int dy = ky - 1, dx = kx - 1;
        for (int kc = 0; kc < 4; ++kc) {
            int kco = kc * 64 + scb * 8;
            const ushort_t* wb = wt + tap * (OCPAD * 256) + kco;
            uint4 av[4], bv[4];
            #pragma unroll
            for (int j = 0; j < 4; j++) {
                int yy = py[j] + dy, xx = pxx[j] + dx;
                bool v = (yy >= 0) & (yy < H) & (xx >= 0) & (xx < W);
                av[j] = v ? *(const uint4*)(sbase + (yy * W + xx) * 256 + kco)
                          : uint4{0u, 0u, 0u, 0u};
                bv[j] = *(const uint4*)(wb + boff[j]);
            }
            #pragma unroll
            for (int j = 0; j < 4; j++) {
                int row = j * 32 + srow;
                *(uint4*)(As + row * 64 + ssc) = av[j];
                *(uint4*)(Bs + row * 64 + ssc) = bv[j];
            }
            __syncthreads();
            #pragma unroll
            for (int ks = 0; ks < 2; ks++) {
                bf16x8 af[4], bg[4];
                #pragma unroll
                for (int mi = 0; mi < 4; mi++) {
                    int rA = wr * 64 + mi * 16 + (ln & 15);
                    int blk = (ks * 4 + (ln >> 4)) ^ (ln & 7);
                    af[mi] = *(const bf16x8*)(As + rA * 64 + blk * 8);
                }
                #pragma unroll
                for (int ni = 0; ni < 4; ni++) {
                    int rB = wc * 64 + ni * 16 + (ln & 15);
                    int blk = (ks * 4 + (ln >> 4)) ^ (ln & 7);
                    bg[ni] = *(const bf16x8*)(Bs + rB * 64 + blk * 8);
                }
                #pragma unroll
                for (int mi = 0; mi < 4; mi++)
                    #pragma unroll
                    for (int ni = 0; ni < 4; ni++)
                        acc[mi][ni] = __builtin_amdgcn_mfma_f32_16x16x32_bf16(af[mi], bg[ni], acc[mi][ni], 0, 0, 0);
            }
            __syncthreads();
        }
    }
    if (MODE == 0) {
        ushort_t* obase = (ushort_t*)dstv + (size_t)n * HW * 256;
        #pragma unroll
        for (int ni = 0; ni < 4; ni++) {
            int oc = oc0 + wc * 64 + ni * 16 + (ln & 15);
            float bv = bias[oc];
            float s = 0.f, q = 0.f;
            #pragma unroll
            for (int mi = 0; mi < 4; mi++) {
                int pb = px0 + wr * 64 + mi * 16 + ((ln >> 4) << 2);
                #pragma unroll
                for (int rr2 = 0; rr2 < 4; rr2++) {
                    int p = pb + rr2;
                    if (p < HW) {
                        float v = acc[mi][ni][rr2] + bv;
                        obase[p * 256 + oc] = f2bf(v);
                        s += v; q += v * v;
                    }
                }
            }
            s += __shfl_xor(s, 16, 64); q += __shfl_xor(q, 16, 64);
            s += __shfl_xor(s, 32, 64); q += __shfl_xor(q, 32, 64);
            s += __shfl_xor(s, 1, 64);  q += __shfl_xor(q, 1, 64);
            s += __shfl_xor(s, 2, 64);  q += __shfl_xor(q, 2, 64);
            s += __shfl_xor(s, 4, 64);  q += __shfl_xor(q, 4, 64);
            if (ln == 0 || ln == 8) {
                int g = (oc0 + wc * 64 + ni * 16 + (ln & 8)) >> 3;
                float* st = stats + (n * 32 + g) * 2;
                atomicAdd(st, s); atomicAdd(st + 1, q);
            }
        }
    } else {
        float* dst = (float*)dstv;
        #pragma unroll
        for (int ni = 0; ni < 4; ni++) {
            int oc = wc * 64 + ni * 16 + (ln & 15);
            if (MODE == 1 ? (oc < 80) : (oc < 26)) {
                float bv = bias[oc];
                int rb = 0, rm = 80, rc = oc; bool rl = false;
                if (MODE == 2) { rb = d_RB[oc]; rm = d_RM[oc]; rc = d_RC[oc]; rl = (oc < 4); }
                #pragma unroll
                for (int mi = 0; mi < 4; mi++) {
                    int pb = px0 + wr * 64 + mi * 16 + ((ln >> 4) << 2);
                    #pragma unroll
                    for (int rr2 = 0; rr2 < 4; rr2++) {
                        int p = pb + rr2;
                        if (p < HW) {
                            float v = acc[mi][ni][rr2] + bv;
                            if (rl) v = fmaxf(v, 0.f);
                            int pg = n * TOTAL_HW + loff + p;
                            dst[rb + (size_t)pg * rm + rc] = v;
                        }
                    }
                }
            }
        }
    }
}

__global__ __launch_bounds__(256) void normL_k(
    ushort_t* __restrict__ buf, const float* __restrict__ stats,
    const float* __restrict__ gw, const float* __restrict__ gb, int HW)
{
    int u = blockIdx.x * 256 + threadIdx.x;
    if (u >= HW * 64) return;
    int per_n = HW * 32;
    int n = (u >= per_n) ? 1 : 0; int r = u - n * per_n;
    int p = r >> 5, g = r & 31;
    const float* st = stats + (n * 32 + g) * 2;
    float cnt = 8.0f * (float)HW;
    float mean = st[0] / cnt;
    float var = st[1] / cnt - mean * mean;
    float inv = rsqrtf(fmaxf(var, 0.f) + 1e-5f);
    ushort_t* ptr = buf + ((size_t)n * HW + p) * 256 + g * 8;
    uint4 din = *(const uint4*)ptr;
    uint4 dout;
    const ushort_t* xi = (const ushort_t*)&din;
    ushort_t* oi = (ushort_t*)&dout;
    #pragma unroll
    for (int i = 0; i < 8; i++) {
        float v = (bf2f(xi[i]) - mean) * inv * gw[g * 8 + i] + gb[g * 8 + i];
        oi[i] = f2bf(fmaxf(v, 0.f));
    }
    *(uint4*)ptr = dout;
}

// ---------------- ws layout (bytes) ----------------
// shared prefix: Stats 0..20,480 | RegBias 20,480..20,608 | TowerWtAll 20,608..9,457,792
//                WtCls 9,457,792..10,047,616 | WtReg 10,047,616..10,637,440
// FAST:  S 10,637,440 | Ac 32,414,848 | Ar 54,192,256 | Br 75,969,664 | end 97,747,072
// FALL:  S 10,637,440 | D 26,202,240 | end 41,767,040   (R6 proven)
#define FAST_BYTES 97747072ull

extern "C" void kernel_launch(void* const* d_in, const int* in_sizes, int n_in,
                              void* d_out, int out_size, void* d_ws, size_t ws_size,
                              hipStream_t stream) {
    const float* feats[5] = {(const float*)d_in[0], (const float*)d_in[1],
                             (const float*)d_in[2], (const float*)d_in[3],
                             (const float*)d_in[4]};
    const float* cls_conv_w = (const float*)d_in[5];
    const float* cls_conv_b = (const float*)d_in[6];
    const float* cls_gn_w   = (const float*)d_in[7];
    const float* cls_gn_b   = (const float*)d_in[8];
    const float* cls_out_w  = (const float*)d_in[9];
    const float* cls_out_b  = (const float*)d_in[10];
    const float* reg_conv_w = (const float*)d_in[11];
    const float* reg_conv_b = (const float*)d_in[12];
    const float* reg_gn_w   = (const float*)d_in[13];
    const float* reg_gn_b   = (const float*)d_in[14];

    char* wsb = (char*)d_ws;
    float* Stats     = (float*)wsb;
    float* RegBias   = (float*)(wsb + 20480);
    ushort_t* TowerWtAll = (ushort_t*)(wsb + 20608);
    ushort_t* WtCls  = (ushort_t*)(wsb + 9457792);
    ushort_t* WtReg  = (ushort_t*)(wsb + 10047616);
    float* outf      = (float*)d_out;

    // weight prep (both paths)
    hipMemsetAsync(d_ws, 0, 20608, stream);
    for (int tw = 0; tw < 2; tw++) {
        const float* conv_w = tw ? reg_conv_w : cls_conv_w;
        for (int L = 0; L < 4; L++)
            wtrans_tower_k<<<256, 256, 0, stream>>>(conv_w + (size_t)L * 589824,
                                                    TowerWtAll + (size_t)(tw * 4 + L) * 589824);
    }
    wtrans_cls_k<<<128, 256, 0, stream>>>(cls_out_w, WtCls);
    wtrans_reg_k<<<128, 256, 0, stream>>>(
        (const float*)d_in[15], (const float*)d_in[17], (const float*)d_in[19],
        (const float*)d_in[21], (const float*)d_in[23], (const float*)d_in[25],
        (const float*)d_in[16], (const float*)d_in[18], (const float*)d_in[20],
        (const float*)d_in[22], (const float*)d_in[24], (const float*)d_in[26],
        WtReg, RegBias);

    if (ws_size >= FAST_BYTES) {
        // ---------------- FAST ----------------
        ushort_t* S  = (ushort_t*)(wsb + 10637440);
        ushort_t* Ac = (ushort_t*)(wsb + 32414848);
        ushort_t* Ar = (ushort_t*)(wsb + 54192256);
        ushort_t* Br = (ushort_t*)(wsb + 75969664);
        // zero padded activation buffers (pads must be 0 each launch)
        hipMemsetAsync(wsb + 10637440, 0, 87109632, stream);

        packF_k<<<2552, 256, 0, stream>>>(feats[0], feats[1], feats[2], feats[3], feats[4], S);

        ushort_t* sc[4] = {S,  Ac, S,  Ac};
        ushort_t* dc[4] = {Ac, S,  Ac, S };
        ushort_t* sr[4] = {S,  Ar, Br, Ar};
        ushort_t* dr[4] = {Ar, Br, Ar, Br};
        for (int L = 0; L < 4; L++) {
            convT_k<<<dim3(320, 2, 2), 256, 0, stream>>>(
                sc[L], sr[L], dc[L], dr[L], TowerWtAll, cls_conv_b, reg_conv_b, Stats, L);
            normF_k<<<10134, 256, 0, stream>>>(
                dc[L], dr[L], Stats, cls_gn_w, reg_gn_w, cls_gn_b, reg_gn_b, L);
        }
        convH_k<<<dim3(320, 1, 2), 256, 0, stream>>>(S, Br, WtCls, WtReg, cls_out_b, RegBias, outf);
    } else {
        // ---------------- FALLBACK (R6) ----------------
        ushort_t* S = (ushort_t*)(wsb + 10637440);
        ushort_t* D = (ushort_t*)(wsb + 26202240);
        const int Hs[5]  = {100, 50, 25, 13, 7};
        const int Ws_[5] = {152, 76, 38, 19, 10};
        const int HWs[5] = {15200, 3800, 950, 247, 70};
        const int TLs[5] = {119, 30, 8, 2, 1};
        const int PTs[5] = {238, 60, 15, 4, 2};
        const int LOFFs[5] = {0, 15200, 19000, 19950, 20197};
        for (int tw = 0; tw < 2; tw++) {
            const float* conv_b = tw ? reg_conv_b : cls_conv_b;
            const float* gn_w   = tw ? reg_gn_w   : cls_gn_w;
            const float* gn_b   = tw ? reg_gn_b   : cls_gn_b;
            for (int l = 0; l < 5; l++) {
                int H = Hs[l], W = Ws_[l], HW = HWs[l], TL = TLs[l];
                packL_k<<<PTs[l] * 8, 256, 0, stream>>>(feats[l], S, HW, PTs[l]);
                ushort_t* cur = S;
                ushort_t* oth = D;
                for (int L = 0; L < 4; L++) {
                    float* st = Stats + (size_t)((tw * 4 + L) * 5 + l) * 128;
                    conv3L_k<0><<<dim3(2 * TL, 2), 256, 0, stream>>>(
                        cur, TowerWtAll + (size_t)(tw * 4 + L) * 589824,
                        conv_b + L * 256, oth, st, H, W, HW, TL, 0);
                    normL_k<<<(HW * 64 + 255) / 256, 256, 0, stream>>>(
                        oth, st, gn_w + L * 256, gn_b + L * 256, HW);
                    ushort_t* t = cur; cur = oth; oth = t;
                }
                if (tw == 0)
                    conv3L_k<1><<<dim3(2 * TL, 1), 256, 0, stream>>>(
                        cur, WtCls, cls_out_b, outf, nullptr, H, W, HW, TL, LOFFs[l]);
                else
                    conv3L_k<2><<<dim3(2 * TL, 1), 256, 0, stream>>>(
                        cur, WtReg, RegBias, outf, nullptr, H, W, HW, TL, LOFFs[l]);
            }
        }
    }
}

// Round 8
// 936.957 us; speedup vs baseline: 3.2355x; 1.1578x over previous
//
#include <hip/hip_runtime.h>
#include <stdint.h>

typedef unsigned short ushort_t;
typedef __bf16 bf16x8 __attribute__((ext_vector_type(8)));
typedef float f32x4 __attribute__((ext_vector_type(4)));

#define TOTAL_HW 20267
#define PTOT 21267          // padded pyramid pixels per batch

// reg-head fused channel mapping (26 channels -> 6 tensors in d_out), f32 element offsets
__constant__ int d_RB[26] = {3242720,3242720,3242720,3242720, 3404856, 3445390,3445390,3445390,
                             3566992, 3607526,3607526,3607526,3607526,3607526,3607526,3607526,3607526,
                             3607526,3607526,3607526,3607526,3607526,3607526,3607526,3607526, 4256070};
__constant__ int d_RM[26] = {4,4,4,4, 1, 3,3,3, 1, 16,16,16,16,16,16,16,16,16,16,16,16,16,16,16,16, 1};
__constant__ int d_RC[26] = {0,1,2,3, 0, 0,1,2, 0, 0,1,2,3,4,5,6,7,8,9,10,11,12,13,14,15, 0};

// level geometry
__constant__ int F_TC[6]   = {0,238,298,314,318,320};
__constant__ int F_TL[5]   = {119,30,8,2,1};
__constant__ int F_W[5]    = {152,76,38,19,10};
__constant__ int F_HW[5]   = {15200,3800,950,247,70};
__constant__ int F_PB[5]   = {0,15708,19764,20844,21159};   // padded pixel base within batch
__constant__ int F_LOFF[5] = {0,15200,19000,19950,20197};
__constant__ int F_PC[6]   = {0,508,764,894,962,1000};      // pad-pixel cumsum
__constant__ int F_H[5]    = {100,50,25,13,7};

__device__ __forceinline__ ushort_t f2bf(float f) {
    union { float f; uint32_t i; } x; x.f = f;
    uint32_t r = x.i + 0x7fffu + ((x.i >> 16) & 1u);   // RNE
    return (ushort_t)(r >> 16);
}
__device__ __forceinline__ float bf2f(ushort_t u) {
    union { uint32_t i; float f; } x; x.i = ((uint32_t)u) << 16; return x.f;
}
__device__ __forceinline__ void gld16(const ushort_t* g, ushort_t* lds) {
    __builtin_amdgcn_global_load_lds((const __attribute__((address_space(1))) void*)g,
                                     (__attribute__((address_space(3))) void*)lds, 16, 0, 0);
}

// ================= weight prep =================
__global__ __launch_bounds__(256) void wtrans_tower_k(const float* __restrict__ src,
                                                      ushort_t* __restrict__ dst)
{
    int id = blockIdx.x * 256 + threadIdx.x;   // 65536
    int oc = id >> 8, ic = id & 255;
    const float* s = src + (size_t)(oc * 256 + ic) * 9;
    ushort_t* d = dst + oc * 256 + ic;
    #pragma unroll
    for (int t = 0; t < 9; t++) d[t * 65536] = f2bf(s[t]);
}
__global__ __launch_bounds__(256) void wtrans_cls_k(const float* __restrict__ src,
                                                    ushort_t* __restrict__ dst)
{
    int id = blockIdx.x * 256 + threadIdx.x;   // 32768
    int oc = id >> 8, ic = id & 255;
    ushort_t* d = dst + oc * 256 + ic;
    if (oc < 80) {
        const float* s = src + (size_t)(oc * 256 + ic) * 9;
        #pragma unroll
        for (int t = 0; t < 9; t++) d[t * 32768] = f2bf(s[t]);
    } else {
        #pragma unroll
        for (int t = 0; t < 9; t++) d[t * 32768] = 0;
    }
}
__global__ __launch_bounds__(256) void wtrans_reg_k(
    const float* bbox_w, const float* ctr_w, const float* dim_w,
    const float* ori_w,  const float* kp_w,  const float* depth_w,
    const float* bbox_b, const float* ctr_b, const float* dim_b,
    const float* ori_b,  const float* kp_b,  const float* depth_b,
    ushort_t* __restrict__ dst, float* __restrict__ RegBias)
{
    int id = blockIdx.x * 256 + threadIdx.x;   // 32768
    int oc = id >> 8, ic = id & 255;
    ushort_t* d = dst + oc * 256 + ic;
    if (oc < 26) {
        const float* s; int c;
        if (oc < 4)       { s = bbox_w;  c = oc; }
        else if (oc < 5)  { s = ctr_w;   c = 0; }
        else if (oc < 8)  { s = dim_w;   c = oc - 5; }
        else if (oc < 9)  { s = ori_w;   c = 0; }
        else if (oc < 25) { s = kp_w;    c = oc - 9; }
        else              { s = depth_w; c = 0; }
        const float* sp = s + (size_t)(c * 256 + ic) * 9;
        #pragma unroll
        for (int t = 0; t < 9; t++) d[t * 32768] = f2bf(sp[t]);
    } else {
        #pragma unroll
        for (int t = 0; t < 9; t++) d[t * 32768] = 0;
    }
    if (id < 26) {
        const float* b; int c;
        if (id < 4)       { b = bbox_b;  c = id; }
        else if (id < 5)  { b = ctr_b;   c = 0; }
        else if (id < 8)  { b = dim_b;   c = id - 5; }
        else if (id < 9)  { b = ori_b;   c = 0; }
        else if (id < 25) { b = kp_b;    c = id - 9; }
        else              { b = depth_b; c = 0; }
        RegBias[id] = b[c];
    }
}

// ================= pad zeroing: borders of the 4 padded activation buffers =================
__global__ __launch_bounds__(256) void pad_k(ushort_t* b0, ushort_t* b1, ushort_t* b2, ushort_t* b3)
{
    int u = blockIdx.x * 256 + threadIdx.x;        // 256000 total
    if (u >= 256000) return;
    int chunk = u & 31; u >>= 5;
    int buf = u & 3; u >>= 2;
    int n = (u >= 1000) ? 1 : 0; int pidx = u - n * 1000;
    int l = 0;
    #pragma unroll
    for (int i = 1; i < 5; i++) if (pidx >= F_PC[i]) l = i;
    int q = pidx - F_PC[l];
    int W = F_W[l], H = F_H[l], Wp = W + 2;
    int py, px;
    if (q < Wp) { py = 0; px = q; }
    else if (q < 2 * Wp) { py = H + 1; px = q - Wp; }
    else { int q2 = q - 2 * Wp; py = 1 + (q2 >> 1); px = (q2 & 1) ? (Wp - 1) : 0; }
    ushort_t* base = b0;
    if (buf == 1) base = b1; else if (buf == 2) base = b2; else if (buf == 3) base = b3;
    *(uint4*)(base + ((size_t)n * PTOT + F_PB[l] + py * Wp + px) * 256 + chunk * 8) = uint4{0u,0u,0u,0u};
}

// ================= pack all levels: f32 NCHW -> padded bf16 NHWC pyramid =================
__global__ __launch_bounds__(256) void packF_k(
    const float* f0, const float* f1, const float* f2,
    const float* f3, const float* f4, ushort_t* __restrict__ S)
{
    __shared__ ushort_t tile[64][65];
    const int PCUM[6] = {0, 1904, 2384, 2504, 2536, 2552};
    const int PT[5]   = {238, 60, 15, 4, 2};
    int bid = blockIdx.x;
    int l = 0;
    #pragma unroll
    for (int i = 1; i < 5; i++) if (bid >= PCUM[i]) l = i;
    int r = bid - PCUM[l];
    int per_n = PT[l] * 4;
    int n = (r >= per_n) ? 1 : 0; r -= n * per_n;
    int pb = r >> 2, cb = r & 3;
    const float* fs = f0;
    if (l == 1) fs = f1; else if (l == 2) fs = f2; else if (l == 3) fs = f3; else if (l == 4) fs = f4;
    int HW = F_HW[l], W = F_W[l], Wp = W + 2;
    int p0 = pb * 64, c0 = cb * 64;
    int t = threadIdx.x;
    #pragma unroll
    for (int i = 0; i < 16; i++) {
        int idx = i * 256 + t; int cl = idx >> 6, pl = idx & 63;
        int p = p0 + pl; ushort_t v = 0;
        if (p < HW) v = f2bf(fs[(size_t)(n * 256 + c0 + cl) * HW + p]);
        tile[cl][pl] = v;
    }
    __syncthreads();
    ushort_t* ob = S + ((size_t)n * PTOT + F_PB[l]) * 256;
    #pragma unroll
    for (int i = 0; i < 16; i++) {
        int idx = i * 256 + t; int pl = idx >> 6, cl = idx & 63;
        int p = p0 + pl;
        if (p < HW) {
            int y = p / W, x = p - y * W;
            ob[((y + 1) * Wp + (x + 1)) * 256 + c0 + cl] = tile[cl][pl];
        }
    }
}

// ================= tower conv: pipelined BK=32, XCD-swizzled =================
__global__ __launch_bounds__(256) void convT_k(
    const ushort_t* __restrict__ srcC, const ushort_t* __restrict__ srcR,
    ushort_t* __restrict__ dstC, ushort_t* __restrict__ dstR,
    const ushort_t* __restrict__ wtAll,
    const float* __restrict__ biasC, const float* __restrict__ biasR,
    float* __restrict__ stats, int L)
{
    __shared__ __align__(16) ushort_t As[2][4096];
    __shared__ __align__(16) ushort_t Bs[2][4096];

    int gid = blockIdx.x;                       // 0..1279
    int xcd = gid & 7, idx = gid >> 3;          // idx 0..159
    int bid = xcd * 40 + (idx >> 2);            // tile id 0..319 (span-local to XCD)
    int oc0 = (idx & 1) * 128;
    int tw = (idx >> 1) & 1;

    const ushort_t* src = tw ? srcR : srcC;
    ushort_t* dst = tw ? dstR : dstC;
    const ushort_t* wt = wtAll + (size_t)(tw * 4 + L) * 589824;
    const float* bias = (tw ? biasR : biasC) + L * 256;

    int l = 0;
    #pragma unroll
    for (int i = 1; i < 5; i++) if (bid >= F_TC[i]) l = i;
    int r = bid - F_TC[l];
    int tl = F_TL[l];
    int n = (r >= tl) ? 1 : 0; int tile = r - n * tl;
    int W = F_W[l], HW = F_HW[l], Wp = W + 2;
    int px0 = tile * 128;
    const ushort_t* sbase = src + ((size_t)n * PTOT + F_PB[l]) * 256;
    ushort_t* obase = dst + ((size_t)n * PTOT + F_PB[l]) * 256;

    int tid = threadIdx.x, wv = tid >> 6, ln = tid & 63;
    int wr = wv >> 1, wc = wv & 1;

    // staging addressing: call j covers rows (wv*2+j)*16 + (ln>>2), LDS chunk' = ln&3
    int aoff[2], boff[2];
    #pragma unroll
    for (int j = 0; j < 2; j++) {
        int rloc = (wv * 2 + j) * 16 + (ln >> 2);
        int p = px0 + rloc; if (p > HW - 1) p = HW - 1;
        int y = p / W, x = p - y * W;
        int c = ((ln & 3) - (rloc >> 1)) & 3;       // global sub-chunk for this LDS slot
        aoff[j] = ((y + 1) * Wp + (x + 1)) * 256 + c * 8;
        boff[j] = (oc0 + rloc) * 256 + c * 8;
    }

    f32x4 acc[4][4];
    #pragma unroll
    for (int mi = 0; mi < 4; mi++)
        #pragma unroll
        for (int ni = 0; ni < 4; ni++) acc[mi][ni] = f32x4{0.f, 0.f, 0.f, 0.f};

    // prologue: it=0 -> tap0 (dy=-1,dx=-1), kc=0
    {
        int tapo = (-Wp - 1) * 256;
        #pragma unroll
        for (int j = 0; j < 2; j++) gld16(sbase + aoff[j] + tapo, &As[0][(wv * 2 + j) * 512]);
        #pragma unroll
        for (int j = 0; j < 2; j++) gld16(wt + boff[j], &Bs[0][(wv * 2 + j) * 512]);
    }

    #pragma unroll 2
    for (int it = 0; it < 72; ++it) {
        __syncthreads();
        int nx = it + 1;
        if (nx < 72) {
            int tp = nx >> 3, kc = (nx & 7) << 5;
            int ky = tp / 3, kx = tp - ky * 3;
            int tapo = ((ky - 1) * Wp + (kx - 1)) * 256 + kc;
            const ushort_t* wtap = wt + tp * 65536 + kc;
            int b = nx & 1;
            #pragma unroll
            for (int j = 0; j < 2; j++) gld16(sbase + aoff[j] + tapo, &As[b][(wv * 2 + j) * 512]);
            #pragma unroll
            for (int j = 0; j < 2; j++) gld16(wtap + boff[j], &Bs[b][(wv * 2 + j) * 512]);
        }
        int b = it & 1;
        bf16x8 af[4], bg[4];
        #pragma unroll
        for (int mi = 0; mi < 4; mi++) {
            int rA = wr * 64 + mi * 16 + (ln & 15);
            int ch = ((ln >> 4) + (rA >> 1)) & 3;
            af[mi] = *(const bf16x8*)&As[b][rA * 32 + ch * 8];
        }
        #pragma unroll
        for (int ni = 0; ni < 4; ni++) {
            int rB = wc * 64 + ni * 16 + (ln & 15);
            int ch = ((ln >> 4) + (rB >> 1)) & 3;
            bg[ni] = *(const bf16x8*)&Bs[b][rB * 32 + ch * 8];
        }
        #pragma unroll
        for (int mi = 0; mi < 4; mi++)
            #pragma unroll
            for (int ni = 0; ni < 4; ni++)
                acc[mi][ni] = __builtin_amdgcn_mfma_f32_16x16x32_bf16(af[mi], bg[ni], acc[mi][ni], 0, 0, 0);
    }

    // epilogue: bias + padded store + GN stats
    #pragma unroll
    for (int ni = 0; ni < 4; ni++) {
        int oc = oc0 + wc * 64 + ni * 16 + (ln & 15);
        float bv = bias[oc];
        float s = 0.f, q = 0.f;
        #pragma unroll
        for (int mi = 0; mi < 4; mi++) {
            int pb = px0 + wr * 64 + mi * 16 + ((ln >> 4) << 2);
            if (pb < HW) {
                int y = pb / W, x = pb - y * W;
                #pragma unroll
                for (int rr2 = 0; rr2 < 4; rr2++) {
                    int p = pb + rr2;
                    if (p < HW) {
                        float v = acc[mi][ni][rr2] + bv;
                        obase[((y + 1) * Wp + (x + 1)) * 256 + oc] = f2bf(v);
                        s += v; q += v * v;
                    }
                    x++; if (x == W) { x = 0; y++; }
                }
            }
        }
        s += __shfl_xor(s, 16, 64); q += __shfl_xor(q, 16, 64);
        s += __shfl_xor(s, 32, 64); q += __shfl_xor(q, 32, 64);
        s += __shfl_xor(s, 1, 64);  q += __shfl_xor(q, 1, 64);
        s += __shfl_xor(s, 2, 64);  q += __shfl_xor(q, 2, 64);
        s += __shfl_xor(s, 4, 64);  q += __shfl_xor(q, 4, 64);
        if (ln == 0 || ln == 8) {
            int g = (oc0 + wc * 64 + ni * 16 + (ln & 8)) >> 3;
            float* st = stats + (size_t)((tw * 4 + L) * 5 + l) * 128 + (n * 32 + g) * 2;
            atomicAdd(st, s); atomicAdd(st + 1, q);
        }
    }
}

// ================= head conv: pipelined BK=32, XCD-swizzled; f32 out =================
__global__ __launch_bounds__(256) void convH_k(
    const ushort_t* __restrict__ srcC, const ushort_t* __restrict__ srcR,
    const ushort_t* __restrict__ wtC, const ushort_t* __restrict__ wtR,
    const float* __restrict__ biasC, const float* __restrict__ biasR,
    float* __restrict__ outF)
{
    __shared__ __align__(16) ushort_t As[2][4096];
    __shared__ __align__(16) ushort_t Bs[2][4096];

    int gid = blockIdx.x;                      // 0..639
    int xcd = gid & 7, idx = gid >> 3;         // idx 0..79
    int bid = xcd * 40 + (idx >> 1);           // tile 0..319
    int mode = idx & 1;

    const ushort_t* src = mode ? srcR : srcC;
    const ushort_t* wt  = mode ? wtR  : wtC;
    const float* bias   = mode ? biasR : biasC;

    int l = 0;
    #pragma unroll
    for (int i = 1; i < 5; i++) if (bid >= F_TC[i]) l = i;
    int r = bid - F_TC[l];
    int tl = F_TL[l];
    int n = (r >= tl) ? 1 : 0; int tile = r - n * tl;
    int W = F_W[l], HW = F_HW[l], Wp = W + 2;
    int px0 = tile * 128;
    const ushort_t* sbase = src + ((size_t)n * PTOT + F_PB[l]) * 256;

    int tid = threadIdx.x, wv = tid >> 6, ln = tid & 63;
    int wr = wv >> 1, wc = wv & 1;

    int aoff[2], boff[2];
    #pragma unroll
    for (int j = 0; j < 2; j++) {
        int rloc = (wv * 2 + j) * 16 + (ln >> 2);
        int p = px0 + rloc; if (p > HW - 1) p = HW - 1;
        int y = p / W, x = p - y * W;
        int c = ((ln & 3) - (rloc >> 1)) & 3;
        aoff[j] = ((y + 1) * Wp + (x + 1)) * 256 + c * 8;
        boff[j] = rloc * 256 + c * 8;
    }

    f32x4 acc[4][4];
    #pragma unroll
    for (int mi = 0; mi < 4; mi++)
        #pragma unroll
        for (int ni = 0; ni < 4; ni++) acc[mi][ni] = f32x4{0.f, 0.f, 0.f, 0.f};

    {
        int tapo = (-Wp - 1) * 256;
        #pragma unroll
        for (int j = 0; j < 2; j++) gld16(sbase + aoff[j] + tapo, &As[0][(wv * 2 + j) * 512]);
        #pragma unroll
        for (int j = 0; j < 2; j++) gld16(wt + boff[j], &Bs[0][(wv * 2 + j) * 512]);
    }

    #pragma unroll 2
    for (int it = 0; it < 72; ++it) {
        __syncthreads();
        int nx = it + 1;
        if (nx < 72) {
            int tp = nx >> 3, kc = (nx & 7) << 5;
            int ky = tp / 3, kx = tp - ky * 3;
            int tapo = ((ky - 1) * Wp + (kx - 1)) * 256 + kc;
            const ushort_t* wtap = wt + tp * 32768 + kc;
            int b = nx & 1;
            #pragma unroll
            for (int j = 0; j < 2; j++) gld16(sbase + aoff[j] + tapo, &As[b][(wv * 2 + j) * 512]);
            #pragma unroll
            for (int j = 0; j < 2; j++) gld16(wtap + boff[j], &Bs[b][(wv * 2 + j) * 512]);
        }
        int b = it & 1;
        bf16x8 af[4], bg[4];
        #pragma unroll
        for (int mi = 0; mi < 4; mi++) {
            int rA = wr * 64 + mi * 16 + (ln & 15);
            int ch = ((ln >> 4) + (rA >> 1)) & 3;
            af[mi] = *(const bf16x8*)&As[b][rA * 32 + ch * 8];
        }
        #pragma unroll
        for (int ni = 0; ni < 4; ni++) {
            int rB = wc * 64 + ni * 16 + (ln & 15);
            int ch = ((ln >> 4) + (rB >> 1)) & 3;
            bg[ni] = *(const bf16x8*)&Bs[b][rB * 32 + ch * 8];
        }
        #pragma unroll
        for (int mi = 0; mi < 4; mi++)
            #pragma unroll
            for (int ni = 0; ni < 4; ni++)
                acc[mi][ni] = __builtin_amdgcn_mfma_f32_16x16x32_bf16(af[mi], bg[ni], acc[mi][ni], 0, 0, 0);
    }

    #pragma unroll
    for (int ni = 0; ni < 4; ni++) {
        int oc = wc * 64 + ni * 16 + (ln & 15);
        bool valid = mode ? (oc < 26) : (oc < 80);
        if (valid) {
            float bv = bias[oc];
            int rb = 0, rm = 80, rc = oc; bool rl = false;
            if (mode) { rb = d_RB[oc]; rm = d_RM[oc]; rc = d_RC[oc]; rl = (oc < 4); }
            #pragma unroll
            for (int mi = 0; mi < 4; mi++) {
                int pb = px0 + wr * 64 + mi * 16 + ((ln >> 4) << 2);
                #pragma unroll
                for (int rr2 = 0; rr2 < 4; rr2++) {
                    int p = pb + rr2;
                    if (p < HW) {
                        float v = acc[mi][ni][rr2] + bv;
                        if (rl) v = fmaxf(v, 0.f);
                        int pg = n * TOTAL_HW + F_LOFF[l] + p;
                        outF[rb + (size_t)pg * rm + rc] = v;
                    }
                }
            }
        }
    }
}

// ================= merged GN finalize+affine+relu (both towers, all levels) =================
__global__ __launch_bounds__(256) void normF_k(
    ushort_t* __restrict__ bufC, ushort_t* __restrict__ bufR,
    const float* __restrict__ stats,
    const float* __restrict__ gwC, const float* __restrict__ gwR,
    const float* __restrict__ gbC, const float* __restrict__ gbR, int L)
{
    int u = blockIdx.x * 256 + threadIdx.x;
    if (u >= 2594176) return;                 // 2tw * 2n * 20267 * 32
    int tw = (u >= 1297088) ? 1 : 0; u -= tw * 1297088;
    int n = (u >= 648544) ? 1 : 0; u -= n * 648544;
    int cp = u >> 5, g = u & 31;
    int l = 0;
    #pragma unroll
    for (int i = 1; i < 5; i++) if (cp >= F_LOFF[i]) l = i;
    int p = cp - F_LOFF[l];
    int W = F_W[l], HW = F_HW[l];
    int y = p / W, x = p - y * W;
    const float* st = stats + (size_t)((tw * 4 + L) * 5 + l) * 128 + (n * 32 + g) * 2;
    float cnt = 8.0f * (float)HW;
    float mean = st[0] / cnt;
    float var = st[1] / cnt - mean * mean;
    float inv = rsqrtf(fmaxf(var, 0.f) + 1e-5f);
    const float* gw = (tw ? gwR : gwC) + L * 256 + g * 8;
    const float* gb = (tw ? gbR : gbC) + L * 256 + g * 8;
    ushort_t* buf = tw ? bufR : bufC;
    ushort_t* ptr = buf + (((size_t)n * PTOT + F_PB[l]) + (y + 1) * (W + 2) + (x + 1)) * 256 + g * 8;
    uint4 din = *(const uint4*)ptr;
    uint4 dout;
    const ushort_t* xi = (const ushort_t*)&din;
    ushort_t* oi = (ushort_t*)&dout;
    #pragma unroll
    for (int i = 0; i < 8; i++) {
        float v = (bf2f(xi[i]) - mean) * inv * gw[i] + gb[i];
        oi[i] = f2bf(fmaxf(v, 0.f));
    }
    *(uint4*)ptr = dout;
}

// ---------------- ws layout (bytes) ----------------
// Stats 0..20,480 | RegBias 20,480..20,608 | TowerWtAll 20,608..9,457,792
// WtCls 9,457,792..10,047,616 | WtReg 10,047,616..10,637,440
// S 10,637,440 | Ac 32,414,848 | Ar 54,192,256 | Br 75,969,664 | end 97,747,072

extern "C" void kernel_launch(void* const* d_in, const int* in_sizes, int n_in,
                              void* d_out, int out_size, void* d_ws, size_t ws_size,
                              hipStream_t stream) {
    const float* feats[5] = {(const float*)d_in[0], (const float*)d_in[1],
                             (const float*)d_in[2], (const float*)d_in[3],
                             (const float*)d_in[4]};
    const float* cls_conv_w = (const float*)d_in[5];
    const float* cls_conv_b = (const float*)d_in[6];
    const float* cls_gn_w   = (const float*)d_in[7];
    const float* cls_gn_b   = (const float*)d_in[8];
    const float* cls_out_w  = (const float*)d_in[9];
    const float* cls_out_b  = (const float*)d_in[10];
    const float* reg_conv_w = (const float*)d_in[11];
    const float* reg_conv_b = (const float*)d_in[12];
    const float* reg_gn_w   = (const float*)d_in[13];
    const float* reg_gn_b   = (const float*)d_in[14];

    char* wsb = (char*)d_ws;
    float* Stats     = (float*)wsb;
    float* RegBias   = (float*)(wsb + 20480);
    ushort_t* TowerWtAll = (ushort_t*)(wsb + 20608);
    ushort_t* WtCls  = (ushort_t*)(wsb + 9457792);
    ushort_t* WtReg  = (ushort_t*)(wsb + 10047616);
    ushort_t* S  = (ushort_t*)(wsb + 10637440);
    ushort_t* Ac = (ushort_t*)(wsb + 32414848);
    ushort_t* Ar = (ushort_t*)(wsb + 54192256);
    ushort_t* Br = (ushort_t*)(wsb + 75969664);
    float* outf  = (float*)d_out;

    hipMemsetAsync(d_ws, 0, 20608, stream);          // Stats + RegBias
    pad_k<<<1000, 256, 0, stream>>>(S, Ac, Ar, Br);  // zero borders only

    for (int tw = 0; tw < 2; tw++) {
        const float* conv_w = tw ? reg_conv_w : cls_conv_w;
        for (int L = 0; L < 4; L++)
            wtrans_tower_k<<<256, 256, 0, stream>>>(conv_w + (size_t)L * 589824,
                                                    TowerWtAll + (size_t)(tw * 4 + L) * 589824);
    }
    wtrans_cls_k<<<128, 256, 0, stream>>>(cls_out_w, WtCls);
    wtrans_reg_k<<<128, 256, 0, stream>>>(
        (const float*)d_in[15], (const float*)d_in[17], (const float*)d_in[19],
        (const float*)d_in[21], (const float*)d_in[23], (const float*)d_in[25],
        (const float*)d_in[16], (const float*)d_in[18], (const float*)d_in[20],
        (const float*)d_in[22], (const float*)d_in[24], (const float*)d_in[26],
        WtReg, RegBias);

    packF_k<<<2552, 256, 0, stream>>>(feats[0], feats[1], feats[2], feats[3], feats[4], S);

    ushort_t* sc[4] = {S,  Ac, S,  Ac};
    ushort_t* dc[4] = {Ac, S,  Ac, S };
    ushort_t* sr[4] = {S,  Ar, Br, Ar};
    ushort_t* dr[4] = {Ar, Br, Ar, Br};
    for (int L = 0; L < 4; L++) {
        convT_k<<<1280, 256, 0, stream>>>(
            sc[L], sr[L], dc[L], dr[L], TowerWtAll, cls_conv_b, reg_conv_b, Stats, L);
        normF_k<<<10134, 256, 0, stream>>>(
            dc[L], dr[L], Stats, cls_gn_w, reg_gn_w, cls_gn_b, reg_gn_b, L);
    }
    convH_k<<<640, 256, 0, stream>>>(S, Br, WtCls, WtReg, cls_out_b, RegBias, outf);
}